// Round 1
// baseline (625.113 us; speedup 1.0000x reference)
//
#include <hip/hip_runtime.h>

#define HH 32
#define TT 512
#define CHUNK 8
#define NCHUNK (TT / CHUNK)

__device__ __forceinline__ float fast_tanh(float z) {
    // tanh(z) = 1 - 2/(exp(2z)+1); exp(2z) = exp2(z * 2*log2(e))
    float e, r;
    float zz = z * 2.88539008177793f;
    asm("v_exp_f32 %0, %1" : "=v"(e) : "v"(zz));
    float d = e + 1.0f;
    asm("v_rcp_f32 %0, %1" : "=v"(r) : "v"(d));
    return __builtin_fmaf(-2.0f, r, 1.0f);
}

// One wave (64 threads) per block; lanes 0..31 = batch b0, lanes 32..63 = batch b1.
// Lane handles hidden row i = lane&31: holds W_ih1[i,:], W_hh1[i,:], W_ih2[i,:],
// W_hh2[i,:] in 128 VGPRs. h/x broadcasts via LDS with group-uniform ds_read_b128.
// Wave-synchronous: explicit s_waitcnt lgkmcnt(0) fences instead of __syncthreads
// (avoids vmcnt(0) drain of the x prefetch).
__global__ __launch_bounds__(64, 2) void rnn_fused(
    const float* __restrict__ x,
    const float* __restrict__ Wih1, const float* __restrict__ Whh1,
    const float* __restrict__ bih1, const float* __restrict__ bhh1,
    const float* __restrict__ Wih2, const float* __restrict__ Whh2,
    const float* __restrict__ bih2, const float* __restrict__ bhh2,
    const float* __restrict__ Wfc, const float* __restrict__ bfc,
    float* __restrict__ out)
{
    __shared__ __align__(16) float x_lds[2][CHUNK * HH];
    __shared__ __align__(16) float h1_lds[2][HH];
    __shared__ __align__(16) float h2_lds[2][HH];

    const int lane = threadIdx.x;
    const int g = lane >> 5;
    const int i = lane & 31;
    const int b = blockIdx.x * 2 + g;

    // --- load weight rows into registers (one-time, L2-cached across blocks) ---
    float wih1[HH], whh1[HH], wih2[HH], whh2[HH];
    {
        const float4* a = (const float4*)(Wih1 + i * HH);
        const float4* c = (const float4*)(Whh1 + i * HH);
        const float4* d2 = (const float4*)(Wih2 + i * HH);
        const float4* e2 = (const float4*)(Whh2 + i * HH);
#pragma unroll
        for (int q = 0; q < 8; ++q) {
            float4 v;
            v = a[q];  wih1[4*q]=v.x; wih1[4*q+1]=v.y; wih1[4*q+2]=v.z; wih1[4*q+3]=v.w;
            v = c[q];  whh1[4*q]=v.x; whh1[4*q+1]=v.y; whh1[4*q+2]=v.z; whh1[4*q+3]=v.w;
            v = d2[q]; wih2[4*q]=v.x; wih2[4*q+1]=v.y; wih2[4*q+2]=v.z; wih2[4*q+3]=v.w;
            v = e2[q]; whh2[4*q]=v.x; whh2[4*q+1]=v.y; whh2[4*q+2]=v.z; whh2[4*q+3]=v.w;
        }
    }
    const float bias1 = bih1[i] + bhh1[i];
    const float bias2 = bih2[i] + bhh2[i];
    const float wfc = Wfc[i];

    const float* xb = x + (size_t)b * (TT * HH);

    // prefetch chunk 0 into registers (t = 0..7, 256 floats = 64 float4 per group)
    float4 r0, r1;
    {
        const float4* src = (const float4*)xb;
        r0 = src[i];
        r1 = src[i + 32];
    }

    float h1vals[HH];
#pragma unroll
    for (int j = 0; j < HH; ++j) h1vals[j] = 0.0f;
    float h2_own = 0.0f;
    h2_lds[g][i] = 0.0f;  // h2_{-1} = 0 (fenced by first chunk-commit fence)

    float4* xl4 = (float4*)&x_lds[g][0];
    const float4* h1l4 = (const float4*)&h1_lds[g][0];
    const float4* h2l4 = (const float4*)&h2_lds[g][0];

    for (int c = 0; c < NCHUNK; ++c) {
        // commit staged chunk to LDS; fence makes it visible to all 32 group lanes
        xl4[i] = r0;
        xl4[i + 32] = r1;
        asm volatile("s_waitcnt lgkmcnt(0)" ::: "memory");
        // issue next chunk's global loads (8 steps of latency to hide)
        {
            const int cn = (c + 1 < NCHUNK) ? c + 1 : c;
            const float4* src = (const float4*)(xb + cn * (CHUNK * HH));
            r0 = src[i];
            r1 = src[i + 32];
        }
#pragma unroll 2
        for (int s = 0; s < CHUNK; ++s) {
            // ---- layer 1: acc = bias1 + W_ih1[i,:]·x_t + W_hh1[i,:]·h1_{t-1} ----
            float p0 = bias1, p1 = 0.0f, p2 = 0.0f, p3 = 0.0f;
#pragma unroll
            for (int j4 = 0; j4 < 8; ++j4) {
                float4 xv = xl4[s * 8 + j4];  // group-uniform broadcast read
                p0 = __builtin_fmaf(wih1[4*j4+0], xv.x, p0);
                p1 = __builtin_fmaf(wih1[4*j4+1], xv.y, p1);
                p2 = __builtin_fmaf(wih1[4*j4+2], xv.z, p2);
                p3 = __builtin_fmaf(wih1[4*j4+3], xv.w, p3);
            }
#pragma unroll
            for (int j4 = 0; j4 < 8; ++j4) {
                p0 = __builtin_fmaf(whh1[4*j4+0], h1vals[4*j4+0], p0);
                p1 = __builtin_fmaf(whh1[4*j4+1], h1vals[4*j4+1], p1);
                p2 = __builtin_fmaf(whh1[4*j4+2], h1vals[4*j4+2], p2);
                p3 = __builtin_fmaf(whh1[4*j4+3], h1vals[4*j4+3], p3);
            }
            float h1n = fast_tanh((p0 + p1) + (p2 + p3));
            h1_lds[g][i] = h1n;
            asm volatile("s_waitcnt lgkmcnt(0)" ::: "memory");  // h1 (and prev h2) visible

            // ---- layer 2: acc = bias2 + W_ih2[i,:]·h1_t + W_hh2[i,:]·h2_{t-1} ----
            float q0 = bias2, q1 = 0.0f, q2 = 0.0f, q3 = 0.0f;
#pragma unroll
            for (int j4 = 0; j4 < 8; ++j4) {
                float4 h1v = h1l4[j4];  // broadcast; also becomes h1_{t} for next step
                float4 h2v = h2l4[j4];  // broadcast of h2_{t-1}
                h1vals[4*j4+0] = h1v.x; h1vals[4*j4+1] = h1v.y;
                h1vals[4*j4+2] = h1v.z; h1vals[4*j4+3] = h1v.w;
                q0 = __builtin_fmaf(wih2[4*j4+0], h1v.x, q0);
                q1 = __builtin_fmaf(wih2[4*j4+1], h1v.y, q1);
                q2 = __builtin_fmaf(wih2[4*j4+2], h1v.z, q2);
                q3 = __builtin_fmaf(wih2[4*j4+3], h1v.w, q3);
                q0 = __builtin_fmaf(whh2[4*j4+0], h2v.x, q0);
                q1 = __builtin_fmaf(whh2[4*j4+1], h2v.y, q1);
                q2 = __builtin_fmaf(whh2[4*j4+2], h2v.z, q2);
                q3 = __builtin_fmaf(whh2[4*j4+3], h2v.w, q3);
            }
            float h2n = fast_tanh((q0 + q1) + (q2 + q3));
            h2_own = h2n;
            h2_lds[g][i] = h2n;  // visibility covered by next step's fence
        }
    }

    // ---- epilogue: out[b] = sum_i h2[i]*Wfc[i] + bfc ----
    h1_lds[g][i] = h2_own * wfc;
    asm volatile("s_waitcnt lgkmcnt(0)" ::: "memory");
    if (i == 0) {
        float sacc = bfc[0];
#pragma unroll
        for (int j = 0; j < HH; ++j) sacc += h1_lds[g][j];
        out[b] = sacc;
    }
}

extern "C" void kernel_launch(void* const* d_in, const int* in_sizes, int n_in,
                              void* d_out, int out_size, void* d_ws, size_t ws_size,
                              hipStream_t stream) {
    const float* x    = (const float*)d_in[0];
    const float* Wih1 = (const float*)d_in[1];
    const float* Whh1 = (const float*)d_in[2];
    const float* bih1 = (const float*)d_in[3];
    const float* bhh1 = (const float*)d_in[4];
    const float* Wih2 = (const float*)d_in[5];
    const float* Whh2 = (const float*)d_in[6];
    const float* bih2 = (const float*)d_in[7];
    const float* bhh2 = (const float*)d_in[8];
    const float* Wfc  = (const float*)d_in[9];
    const float* bfc  = (const float*)d_in[10];
    float* out = (float*)d_out;

    rnn_fused<<<dim3(2048), dim3(64), 0, stream>>>(
        x, Wih1, Whh1, bih1, bhh1, Wih2, Whh2, bih2, bhh2, Wfc, bfc, out);
}

// Round 2
// 556.287 us; speedup vs baseline: 1.1237x; 1.1237x over previous
//
#include <hip/hip_runtime.h>

#define HH 32
#define TT 512
#define CHUNK 8
#define NCHUNK (TT / CHUNK)

__device__ __forceinline__ float fast_tanh(float z) {
    // tanh(z) = 1 - 2/(exp(2z)+1); exp2-based, ~1e-7 abs err
    float e, r;
    float zz = z * 2.88539008177793f;  // 2*log2(e)
    asm("v_exp_f32 %0, %1" : "=v"(e) : "v"(zz));
    float d = e + 1.0f;
    asm("v_rcp_f32 %0, %1" : "=v"(r) : "v"(d));
    return __builtin_fmaf(-2.0f, r, 1.0f);
}

// One wave/block; lanes 0..31 = batch b0, lanes 32..63 = batch b1.
// Lane owns hidden row i of all 4 weight matrices in VGPRs (128 regs).
// h/x broadcast via group-uniform ds_read_b128. Wave-synchronous fences
// (s_waitcnt lgkmcnt(0)) instead of __syncthreads — no vmcnt drain, so the
// x prefetch stays in flight across steps.
// waves_per_eu(2,2): pin allocator budget to 256 VGPR so the ~195-reg live
// set (weights + h1r + prefetch) stays spill-free (R1 showed a 128-reg
// allocation with ~200 extra VALU instrs/step).
__global__ void __launch_bounds__(64) __attribute__((amdgpu_waves_per_eu(2, 2)))
rnn_fused(
    const float* __restrict__ x,
    const float* __restrict__ Wih1, const float* __restrict__ Whh1,
    const float* __restrict__ bih1, const float* __restrict__ bhh1,
    const float* __restrict__ Wih2, const float* __restrict__ Whh2,
    const float* __restrict__ bih2, const float* __restrict__ bhh2,
    const float* __restrict__ Wfc, const float* __restrict__ bfc,
    float* __restrict__ out)
{
    __shared__ __align__(16) float x_lds[2][CHUNK * HH];
    __shared__ __align__(16) float h1_lds[2][HH];
    __shared__ __align__(16) float h2_lds[2][HH];

    const int lane = threadIdx.x;
    const int g = lane >> 5;
    const int i = lane & 31;
    const int b = blockIdx.x * 2 + g;

    // ---- weight rows in registers: 32 float4 = 128 VGPRs ----
    float4 w1[8], u1[8], w2[8], u2[8];
#pragma unroll
    for (int q = 0; q < 8; ++q) {
        w1[q] = ((const float4*)(Wih1 + i * HH))[q];
        u1[q] = ((const float4*)(Whh1 + i * HH))[q];
        w2[q] = ((const float4*)(Wih2 + i * HH))[q];
        u2[q] = ((const float4*)(Whh2 + i * HH))[q];
    }
    const float bias1 = bih1[i] + bhh1[i];
    const float bias2 = bih2[i] + bhh2[i];
    const float wfc = Wfc[i];

    const float* xb = x + (size_t)b * (TT * HH);

    // prefetch chunk 0 (8 timesteps = 64 float4 per group)
    float4 r0 = ((const float4*)xb)[i];
    float4 r1 = ((const float4*)xb)[i + 32];

    // h1_{t-1} broadcast values, live across steps in regs (no copy movs)
    float4 h1r[8];
#pragma unroll
    for (int j = 0; j < 8; ++j) h1r[j] = make_float4(0.f, 0.f, 0.f, 0.f);
    float h2_own = 0.0f;
    h2_lds[g][i] = 0.0f;  // h2_{-1}=0; visible after first chunk fence

    float4* xl4 = (float4*)&x_lds[g][0];
    const float4* h1l4 = (const float4*)&h1_lds[g][0];
    const float4* h2l4 = (const float4*)&h2_lds[g][0];

    for (int c = 0; c < NCHUNK; ++c) {
        // commit staged x chunk (ds_write waits vmcnt for r0/r1 internally)
        xl4[i] = r0;
        xl4[i + 32] = r1;
        asm volatile("s_waitcnt lgkmcnt(0)" ::: "memory");
        // issue next chunk's global loads — 8 steps (~2500 cyc) to hide them
        {
            const int cn = (c + 1 < NCHUNK) ? c + 1 : c;
            const float4* src = (const float4*)(xb + cn * (CHUNK * HH));
            r0 = src[i];
            r1 = src[i + 32];
        }
#pragma unroll
        for (int s = 0; s < CHUNK; ++s) {
            // ---- layer 1: bias1 + W_ih1[i,:]·x_t + W_hh1[i,:]·h1_{t-1} ----
            float p0 = bias1, p1 = 0.f, p2 = 0.f, p3 = 0.f;
#pragma unroll
            for (int j = 0; j < 8; ++j) {
                float4 xv = xl4[s * 8 + j];  // immediate-offset broadcast read
                p0 = __builtin_fmaf(w1[j].x, xv.x, p0);
                p1 = __builtin_fmaf(w1[j].y, xv.y, p1);
                p2 = __builtin_fmaf(w1[j].z, xv.z, p2);
                p3 = __builtin_fmaf(w1[j].w, xv.w, p3);
            }
#pragma unroll
            for (int j = 0; j < 8; ++j) {
                p0 = __builtin_fmaf(u1[j].x, h1r[j].x, p0);
                p1 = __builtin_fmaf(u1[j].y, h1r[j].y, p1);
                p2 = __builtin_fmaf(u1[j].z, h1r[j].z, p2);
                p3 = __builtin_fmaf(u1[j].w, h1r[j].w, p3);
            }
            float h1n = fast_tanh((p0 + p1) + (p2 + p3));
            h1_lds[g][i] = h1n;
            asm volatile("s_waitcnt lgkmcnt(0)" ::: "memory");  // h1_t + h2_{t-1} visible

            // ---- layer 2: bias2 + W_ih2[i,:]·h1_t + W_hh2[i,:]·h2_{t-1} ----
            float q0 = bias2, q1 = 0.f, q2 = 0.f, q3 = 0.f;
#pragma unroll
            for (int j = 0; j < 8; ++j) {
                float4 h1v = h1l4[j];
                float4 h2v = h2l4[j];
                h1r[j] = h1v;  // SSA rename: becomes next step's h1_{t-1}
                q0 = __builtin_fmaf(w2[j].x, h1v.x, q0);
                q1 = __builtin_fmaf(w2[j].y, h1v.y, q1);
                q2 = __builtin_fmaf(w2[j].z, h1v.z, q2);
                q3 = __builtin_fmaf(w2[j].w, h1v.w, q3);
                q0 = __builtin_fmaf(u2[j].x, h2v.x, q0);
                q1 = __builtin_fmaf(u2[j].y, h2v.y, q1);
                q2 = __builtin_fmaf(u2[j].z, h2v.z, q2);
                q3 = __builtin_fmaf(u2[j].w, h2v.w, q3);
            }
            float h2n = fast_tanh((q0 + q1) + (q2 + q3));
            h2_own = h2n;
            h2_lds[g][i] = h2n;  // visibility via next step's fence
        }
    }

    // ---- epilogue: out[b] = Σ_i h2[i]*Wfc[i] + bfc ----
    h1_lds[g][i] = h2_own * wfc;
    asm volatile("s_waitcnt lgkmcnt(0)" ::: "memory");
    if (i == 0) {
        float sacc = bfc[0];
#pragma unroll
        for (int j = 0; j < HH; ++j) sacc += h1_lds[g][j];
        out[b] = sacc;
    }
}

extern "C" void kernel_launch(void* const* d_in, const int* in_sizes, int n_in,
                              void* d_out, int out_size, void* d_ws, size_t ws_size,
                              hipStream_t stream) {
    const float* x    = (const float*)d_in[0];
    const float* Wih1 = (const float*)d_in[1];
    const float* Whh1 = (const float*)d_in[2];
    const float* bih1 = (const float*)d_in[3];
    const float* bhh1 = (const float*)d_in[4];
    const float* Wih2 = (const float*)d_in[5];
    const float* Whh2 = (const float*)d_in[6];
    const float* bih2 = (const float*)d_in[7];
    const float* bhh2 = (const float*)d_in[8];
    const float* Wfc  = (const float*)d_in[9];
    const float* bfc  = (const float*)d_in[10];
    float* out = (float*)d_out;

    rnn_fused<<<dim3(2048), dim3(64), 0, stream>>>(
        x, Wih1, Whh1, bih1, bhh1, Wih2, Whh2, bih2, bhh2, Wfc, bfc, out);
}